// Round 2
// baseline (16.273 us; speedup 1.0000x reference)
//
#include <hip/hip_runtime.h>

// ANFIS (I=2, M=2, R=4) fused single pass, elementwise over N.
// mu[i][m] = 1/(1+|(x_i - c[i][m])/a[i][m]|^(2 b[i][m]))
// out[n]   = sum_{m,n2} mu0[m] mu1[n2] (W[r].x + Bd[r]) / ((mu00+mu01)(mu10+mu11))
// with r = m*2 + n2.

__global__ __launch_bounds__(256) void anfis_kernel(
    const float* __restrict__ x,    // [2][N]
    const float* __restrict__ a,    // [2][2]
    const float* __restrict__ b,    // [2][2]
    const float* __restrict__ c,    // [2][2]
    const float* __restrict__ W,    // [4][2]
    const float* __restrict__ Bd,   // [4]
    float* __restrict__ out,        // [N]
    int N)
{
    // Per-MF derived constants (uniform; scalar-load + broadcast, negligible cost).
    float ia[2][2], nca[2][2], tb[2][2];
#pragma unroll
    for (int i = 0; i < 2; ++i) {
#pragma unroll
        for (int m = 0; m < 2; ++m) {
            float av = a[i * 2 + m];
            float bv = b[i * 2 + m];
            float cv = c[i * 2 + m];
            float r  = 1.0f / av;
            ia[i][m]  = r;
            nca[i][m] = -cv * r;     // t = fma(x, 1/a, -c/a) = (x-c)/a
            tb[i][m]  = 2.0f * bv;
        }
    }
    float w0[4], w1[4], bd[4];
#pragma unroll
    for (int r = 0; r < 4; ++r) {
        w0[r] = W[r * 2 + 0];
        w1[r] = W[r * 2 + 1];
        bd[r] = Bd[r];
    }

    int idx = (blockIdx.x * blockDim.x + threadIdx.x) * 4;
    if (idx >= N) return;

    float4 v0 = *reinterpret_cast<const float4*>(x + idx);       // x row 0
    float4 v1 = *reinterpret_cast<const float4*>(x + N + idx);   // x row 1

    float xs0[4] = {v0.x, v0.y, v0.z, v0.w};
    float xs1[4] = {v1.x, v1.y, v1.z, v1.w};
    float res[4];

#pragma unroll
    for (int k = 0; k < 4; ++k) {
        float x0 = xs0[k], x1 = xs1[k];

        float mu0[2], mu1[2];
#pragma unroll
        for (int m = 0; m < 2; ++m) {
            // input 0: |t|^(2b) = exp2(2b * log2|t|); t=0 -> log2=-inf -> exp2=0 -> mu=1
            float t = fabsf(fmaf(x0, ia[0][m], nca[0][m]));
            float u = __builtin_amdgcn_exp2f(tb[0][m] * __builtin_amdgcn_logf(t));
            mu0[m] = __builtin_amdgcn_rcpf(1.0f + u);
            // input 1
            float s = fabsf(fmaf(x1, ia[1][m], nca[1][m]));
            float v = __builtin_amdgcn_exp2f(tb[1][m] * __builtin_amdgcn_logf(s));
            mu1[m] = __builtin_amdgcn_rcpf(1.0f + v);
        }

        // Denominator factors over the product structure.
        float den = (mu0[0] + mu0[1]) * (mu1[0] + mu1[1]);

        float num = 0.0f;
#pragma unroll
        for (int m = 0; m < 2; ++m) {
#pragma unroll
            for (int n2 = 0; n2 < 2; ++n2) {
                int r = m * 2 + n2;
                float f = fmaf(w0[r], x0, fmaf(w1[r], x1, bd[r]));
                num = fmaf(mu0[m] * mu1[n2], f, num);
            }
        }
        res[k] = num * __builtin_amdgcn_rcpf(den);
    }

    float4 o = {res[0], res[1], res[2], res[3]};
    *reinterpret_cast<float4*>(out + idx) = o;
}

extern "C" void kernel_launch(void* const* d_in, const int* in_sizes, int n_in,
                              void* d_out, int out_size, void* d_ws, size_t ws_size,
                              hipStream_t stream) {
    const float* x  = (const float*)d_in[0];
    const float* a  = (const float*)d_in[1];
    const float* b  = (const float*)d_in[2];
    const float* c  = (const float*)d_in[3];
    const float* W  = (const float*)d_in[4];
    const float* Bd = (const float*)d_in[5];
    float* out = (float*)d_out;

    int N = out_size;                 // 4,194,304
    int n4 = (N + 3) / 4;             // elements are processed 4/thread
    int block = 256;
    int grid = (n4 + block - 1) / block;

    anfis_kernel<<<grid, block, 0, stream>>>(x, a, b, c, W, Bd, out, N);
}

// Round 3
// 13.343 us; speedup vs baseline: 1.2196x; 1.2196x over previous
//
#include <hip/hip_runtime.h>

// ANFIS (I=2, M=2, R=4) fused single pass, elementwise over N.
//
// Algebra: with u[i][m] = |(x_i-c)/a|^(2b), mu = 1/(1+u), the normalized
// rule weight for rule (m,n) simplifies (multiply num & den by prod(1+u)):
//   norm_{mn} = (1+u[0][1-m]) (1+u[1][1-n]) / ((2+u00+u01)(2+u10+u11))
// -> exactly ONE rcp per element, no per-MF divides.
//
// Fast path: when all b == 2 (true for this dataset), |t|^(2b) = (t^2)^2,
// eliminating all log/exp. Wave-uniform branch, general path kept as fallback.

__global__ __launch_bounds__(256) void anfis_kernel(
    const float* __restrict__ x,    // [2][N]
    const float* __restrict__ a,    // [2][2]
    const float* __restrict__ b,    // [2][2]
    const float* __restrict__ c,    // [2][2]
    const float* __restrict__ W,    // [4][2]
    const float* __restrict__ Bd,   // [4]
    float* __restrict__ out,        // [N]
    int N)
{
    // Per-MF derived constants (uniform scalar loads, L2-broadcast).
    float ia[2][2], nca[2][2], tb[2][2];
    bool all_b2 = true;
#pragma unroll
    for (int i = 0; i < 2; ++i) {
#pragma unroll
        for (int m = 0; m < 2; ++m) {
            float av = a[i * 2 + m];
            float bv = b[i * 2 + m];
            float cv = c[i * 2 + m];
            float r  = 1.0f / av;
            ia[i][m]  = r;
            nca[i][m] = -cv * r;     // t = fma(x, 1/a, -c/a) = (x-c)/a
            tb[i][m]  = 2.0f * bv;
            all_b2 = all_b2 && (bv == 2.0f);
        }
    }
    float w0[4], w1[4], bd[4];
#pragma unroll
    for (int r = 0; r < 4; ++r) {
        w0[r] = W[r * 2 + 0];
        w1[r] = W[r * 2 + 1];
        bd[r] = Bd[r];
    }

    int idx = (blockIdx.x * blockDim.x + threadIdx.x) * 8;
    if (idx >= N) return;

    // 8 elements/thread: 2x float4 per input row, issued up front for ILP.
    const float4* p0 = reinterpret_cast<const float4*>(x + idx);
    const float4* p1 = reinterpret_cast<const float4*>(x + N + idx);
    float4 v0a = p0[0], v0b = p0[1];
    float4 v1a = p1[0], v1b = p1[1];

    float xs0[8] = {v0a.x, v0a.y, v0a.z, v0a.w, v0b.x, v0b.y, v0b.z, v0b.w};
    float xs1[8] = {v1a.x, v1a.y, v1a.z, v1a.w, v1b.x, v1b.y, v1b.z, v1b.w};
    float res[8];

    if (all_b2) {
#pragma unroll
        for (int k = 0; k < 8; ++k) {
            float x0 = xs0[k], x1 = xs1[k];
            // u = t^4 per MF (b==2)
            float t00 = fmaf(x0, ia[0][0], nca[0][0]); t00 *= t00;
            float t01 = fmaf(x0, ia[0][1], nca[0][1]); t01 *= t01;
            float t10 = fmaf(x1, ia[1][0], nca[1][0]); t10 *= t10;
            float t11 = fmaf(x1, ia[1][1], nca[1][1]); t11 *= t11;
            float A0 = fmaf(t00, t00, 1.0f);   // 1+u00
            float A1 = fmaf(t01, t01, 1.0f);   // 1+u01
            float B0 = fmaf(t10, t10, 1.0f);
            float B1 = fmaf(t11, t11, 1.0f);

            float den = (A0 + A1) * (B0 + B1);

            // rule r = m*2+n, weight = A_{1-m} * B_{1-n}
            float f0 = fmaf(w0[0], x0, fmaf(w1[0], x1, bd[0]));
            float f1 = fmaf(w0[1], x0, fmaf(w1[1], x1, bd[1]));
            float f2 = fmaf(w0[2], x0, fmaf(w1[2], x1, bd[2]));
            float f3 = fmaf(w0[3], x0, fmaf(w1[3], x1, bd[3]));
            float num = (A1 * B1) * f0;
            num = fmaf(A1 * B0, f1, num);
            num = fmaf(A0 * B1, f2, num);
            num = fmaf(A0 * B0, f3, num);

            res[k] = num * __builtin_amdgcn_rcpf(den);
        }
    } else {
#pragma unroll
        for (int k = 0; k < 8; ++k) {
            float x0 = xs0[k], x1 = xs1[k];
            float u00 = __builtin_amdgcn_exp2f(tb[0][0] * __builtin_amdgcn_logf(fabsf(fmaf(x0, ia[0][0], nca[0][0]))));
            float u01 = __builtin_amdgcn_exp2f(tb[0][1] * __builtin_amdgcn_logf(fabsf(fmaf(x0, ia[0][1], nca[0][1]))));
            float u10 = __builtin_amdgcn_exp2f(tb[1][0] * __builtin_amdgcn_logf(fabsf(fmaf(x1, ia[1][0], nca[1][0]))));
            float u11 = __builtin_amdgcn_exp2f(tb[1][1] * __builtin_amdgcn_logf(fabsf(fmaf(x1, ia[1][1], nca[1][1]))));
            float A0 = 1.0f + u00, A1 = 1.0f + u01;
            float B0 = 1.0f + u10, B1 = 1.0f + u11;
            float den = (A0 + A1) * (B0 + B1);
            float f0 = fmaf(w0[0], x0, fmaf(w1[0], x1, bd[0]));
            float f1 = fmaf(w0[1], x0, fmaf(w1[1], x1, bd[1]));
            float f2 = fmaf(w0[2], x0, fmaf(w1[2], x1, bd[2]));
            float f3 = fmaf(w0[3], x0, fmaf(w1[3], x1, bd[3]));
            float num = (A1 * B1) * f0;
            num = fmaf(A1 * B0, f1, num);
            num = fmaf(A0 * B1, f2, num);
            num = fmaf(A0 * B0, f3, num);
            res[k] = num * __builtin_amdgcn_rcpf(den);
        }
    }

    float4 oA = {res[0], res[1], res[2], res[3]};
    float4 oB = {res[4], res[5], res[6], res[7]};
    float4* po = reinterpret_cast<float4*>(out + idx);
    po[0] = oA;
    po[1] = oB;
}

extern "C" void kernel_launch(void* const* d_in, const int* in_sizes, int n_in,
                              void* d_out, int out_size, void* d_ws, size_t ws_size,
                              hipStream_t stream) {
    const float* x  = (const float*)d_in[0];
    const float* a  = (const float*)d_in[1];
    const float* b  = (const float*)d_in[2];
    const float* c  = (const float*)d_in[3];
    const float* W  = (const float*)d_in[4];
    const float* Bd = (const float*)d_in[5];
    float* out = (float*)d_out;

    int N = out_size;                 // 4,194,304
    int n8 = (N + 7) / 8;             // 8 elements per thread
    int block = 256;
    int grid = (n8 + block - 1) / block;   // 2048 blocks

    anfis_kernel<<<grid, block, 0, stream>>>(x, a, b, c, W, Bd, out, N);
}